// Round 20
// baseline (274.990 us; speedup 1.0000x reference)
//
#include <hip/hip_runtime.h>
#include <hip/hip_bf16.h>
#include <cmath>
#include <cstdint>
#include <cstddef>

// Problem constants: B=4, C=256, H=W=256, DS=4 -> h=w=64, N=4096, Cq=16
typedef unsigned short u16;
typedef __attribute__((ext_vector_type(8))) __bf16 bf16x8;
typedef __attribute__((ext_vector_type(4))) float f32x4;
typedef __attribute__((ext_vector_type(8))) unsigned short us8;
typedef __attribute__((ext_vector_type(4))) unsigned short us4;

// Workspace layout (bytes)
static const size_t OFF_XD32  = 0;            // [B][C][4096] fp32 xd; aliased by ods (bf16) after k_qkv
static const size_t OFF_QT    = 16777216;     // [B][4096][16] fp32, 1 MB
static const size_t OFF_KHI   = 17825792;     // [B][4096][16] u16 bf16-hi of k, 512 KB
static const size_t OFF_KLO   = 18350080;     // [B][4096][16] u16 bf16-lo of k, 512 KB
static const size_t OFF_VT    = 18874368;     // [B][256][4096] bf16 (V transposed), 8 MB
static const size_t OFF_WF    = 27262976;     // Wv A-frags [16 rt][8 ks][64 lane][8 j] bf16, 128 KB
static const size_t OFF_SPART = 27394048;     // [256 qk-blocks][32] fp32 partial col-sums, 32 KB

__device__ __forceinline__ void gl2lds16(const void* gsrc, void* ldst) {
  __builtin_amdgcn_global_load_lds(
      (const __attribute__((address_space(1))) unsigned int*)gsrc,
      (__attribute__((address_space(3))) unsigned int*)ldst, 16, 0, 0);
}

__device__ __forceinline__ float hmax4(float4 v) {
  return fmaxf(fmaxf(v.x, v.y), fmaxf(v.z, v.w));
}

__device__ __forceinline__ float bf2f(u16 u) {
  return __bfloat162float(__builtin_bit_cast(__hip_bfloat16, u));
}

// ---------------- fused: Wv->A-frags (blocks 0..15) + maxpool (blocks 16..16399) ----------------
__global__ __launch_bounds__(256) void k_pre(const float* __restrict__ x,
                                             const float* __restrict__ Wv,
                                             float* __restrict__ xd32,
                                             u16* __restrict__ Wf) {
  const int tid = threadIdx.x;
  if (blockIdx.x < 16) {
    const int rt = blockIdx.x;
#pragma unroll
    for (int i = 0; i < 2; ++i) {
      int s = tid + i * 256;           // 0..511 = ks*64 + lane
      int ks = s >> 6, lane = s & 63;
      const float* src = Wv + (size_t)(rt * 16 + (lane & 15)) * 256u + ks * 32 + (lane >> 4) * 8;
      float4 a = *reinterpret_cast<const float4*>(src);
      float4 b = *reinterpret_cast<const float4*>(src + 4);
      us8 o;
      o[0] = __builtin_bit_cast(u16, __float2bfloat16(a.x));
      o[1] = __builtin_bit_cast(u16, __float2bfloat16(a.y));
      o[2] = __builtin_bit_cast(u16, __float2bfloat16(a.z));
      o[3] = __builtin_bit_cast(u16, __float2bfloat16(a.w));
      o[4] = __builtin_bit_cast(u16, __float2bfloat16(b.x));
      o[5] = __builtin_bit_cast(u16, __float2bfloat16(b.y));
      o[6] = __builtin_bit_cast(u16, __float2bfloat16(b.z));
      o[7] = __builtin_bit_cast(u16, __float2bfloat16(b.w));
      *reinterpret_cast<us8*>(Wf + ((size_t)((rt * 8 + ks) * 64 + lane)) * 8u) = o;
    }
  } else {
    unsigned idx = (blockIdx.x - 16) * 256u + tid;     // < 4*256*64*64
    unsigned xo = idx & 63u;
    unsigned yo = (idx >> 6) & 63u;
    unsigned bc = idx >> 12;                           // b*256 + c
    const float* base = x + (size_t)bc * 65536u + yo * 1024u + xo * 4u;
    float m = -1e30f;
#pragma unroll
    for (int dy = 0; dy < 4; ++dy) {
      float4 v = *reinterpret_cast<const float4*>(base + dy * 256);
      m = fmaxf(m, hmax4(v));
    }
    xd32[(size_t)bc * 4096u + yo * 64u + xo] = m;
  }
}

// ---------------- fused q/k convs + V MFMA gemm (block-role split) ----------------
__global__ __launch_bounds__(512) void k_qkv(const float* __restrict__ xd32,
                                             const u16* __restrict__ Wf, const float* __restrict__ bv,
                                             const float* __restrict__ Wq, const float* __restrict__ bq,
                                             const float* __restrict__ Wk, const float* __restrict__ bk,
                                             float* __restrict__ qT,
                                             u16* __restrict__ khi, u16* __restrict__ klo,
                                             u16* __restrict__ vT, float* __restrict__ Spart) {
  __shared__ char smem[65536];
  const int tid = threadIdx.x;

  if (blockIdx.x < 256) {
    // ---------- vgemm role ----------
    u16 (*Bf)[8][64][8] = reinterpret_cast<u16(*)[8][64][8]>(smem);   // 32 KB
    const int blk = blockIdx.x;
    const int b = blk >> 6, n0 = (blk & 63) * 64;
    const int w = tid >> 6, lane = tid & 63;

#pragma unroll
    for (int p = 0; p < 8; ++p) {
      int idx = p * 512 + tid;         // 0..4095 float4 slots
      int k = idx >> 4, q4 = idx & 15;
      float4 v = *reinterpret_cast<const float4*>(
          xd32 + ((size_t)b * 256 + k) * 4096u + n0 + q4 * 4);
      int ks = k >> 5, kl = (k >> 3) & 3, j = k & 7;
      int ct = q4 >> 2, nb = (q4 & 3) * 4;
      Bf[ct][ks][kl * 16 + nb + 0][j] = __builtin_bit_cast(u16, __float2bfloat16(v.x));
      Bf[ct][ks][kl * 16 + nb + 1][j] = __builtin_bit_cast(u16, __float2bfloat16(v.y));
      Bf[ct][ks][kl * 16 + nb + 2][j] = __builtin_bit_cast(u16, __float2bfloat16(v.z));
      Bf[ct][ks][kl * 16 + nb + 3][j] = __builtin_bit_cast(u16, __float2bfloat16(v.w));
    }
    __syncthreads();

    f32x4 acc[2][4];
#pragma unroll
    for (int r = 0; r < 2; ++r)
#pragma unroll
      for (int ct = 0; ct < 4; ++ct) acc[r][ct] = (f32x4){0.f, 0.f, 0.f, 0.f};
    for (int ks = 0; ks < 8; ++ks) {
      bf16x8 Bv[4];
#pragma unroll
      for (int ct = 0; ct < 4; ++ct)
        Bv[ct] = __builtin_bit_cast(bf16x8, *reinterpret_cast<const us8*>(&Bf[ct][ks][lane][0]));
#pragma unroll
      for (int r = 0; r < 2; ++r) {
        int rt = w * 2 + r;
        bf16x8 Av = __builtin_bit_cast(bf16x8,
            *reinterpret_cast<const us8*>(Wf + ((size_t)((rt * 8 + ks) * 64 + lane)) * 8u));
#pragma unroll
        for (int ct = 0; ct < 4; ++ct)
          acc[r][ct] = __builtin_amdgcn_mfma_f32_16x16x32_bf16(Av, Bv[ct], acc[r][ct], 0, 0, 0);
      }
    }

#pragma unroll
    for (int r = 0; r < 2; ++r) {
      int row0 = (w * 2 + r) * 16 + (lane >> 4) * 4;
#pragma unroll
      for (int rr = 0; rr < 4; ++rr) {
        int c = row0 + rr;
        float bb = bv[c];
        u16* dst = vT + ((size_t)b * 256 + c) * 4096u + n0 + (lane & 15);
#pragma unroll
        for (int ct = 0; ct < 4; ++ct)
          dst[ct * 16] = __builtin_bit_cast(u16, __float2bfloat16(acc[r][ct][rr] + bb));
      }
    }
  } else {
    // ---------- qk role: fp32 exact convs + col sums; k stored pre-split hi/lo ----------
    float (*xs)[64] = reinterpret_cast<float(*)[64]>(smem);   // 64 KB
    const int qb = blockIdx.x - 256;
    const int b = qb >> 6, n0 = (qb & 63) * 64;
    {
      const float* src = xd32 + (size_t)b * 1048576u + n0;
#pragma unroll
      for (int i = 0; i < 8; ++i) {
        int slot = tid + i * 512;      // 0..4095 float4 slots
        int c = slot >> 4, q4 = slot & 15;
        *reinterpret_cast<float4*>(&xs[c][q4 * 4]) =
            *reinterpret_cast<const float4*>(src + (size_t)c * 4096u + q4 * 4);
      }
    }
    __syncthreads();
    const int o = tid >> 4, t4 = tid & 15;   // o 0..31; tokens t4*4..+4
    const float* wrow = (o < 16) ? (Wq + (size_t)o * 256u) : (Wk + (size_t)(o - 16) * 256u);
    float a0 = 0.f, a1 = 0.f, a2 = 0.f, a3 = 0.f;
    for (int c = 0; c < 256; ++c) {
      float w = wrow[c];
      float4 xv = *reinterpret_cast<const float4*>(&xs[c][t4 * 4]);
      a0 = fmaf(w, xv.x, a0);
      a1 = fmaf(w, xv.y, a1);
      a2 = fmaf(w, xv.z, a2);
      a3 = fmaf(w, xv.w, a3);
    }
    int oo = (o < 16) ? o : (o - 16);
    float bb = (o < 16) ? bq[oo] : bk[oo];
    float v0 = a0 + bb, v1 = a1 + bb, v2 = a2 + bb, v3 = a3 + bb;
    size_t base = ((size_t)b * 4096u + n0 + t4 * 4) * 16u + oo;
    if (o < 16) {
      qT[base]      = v0;
      qT[base + 16] = v1;
      qT[base + 32] = v2;
      qT[base + 48] = v3;
    } else {
      float vv[4] = {v0, v1, v2, v3};
#pragma unroll
      for (int j = 0; j < 4; ++j) {
        __hip_bfloat16 h = __float2bfloat16(vv[j]);
        float fh = __bfloat162float(h);
        __hip_bfloat16 lo = __float2bfloat16(vv[j] - fh);
        khi[base + 16 * j] = __builtin_bit_cast(u16, h);
        klo[base + 16 * j] = __builtin_bit_cast(u16, lo);
      }
    }
    float s = a0 + a1 + a2 + a3;
    s += __shfl_xor(s, 1); s += __shfl_xor(s, 2);
    s += __shfl_xor(s, 4); s += __shfl_xor(s, 8);
    if (t4 == 0) Spart[(size_t)qb * 32u + o] = s;
  }
}

// ---------------- flash: 512 blocks x 256 threads (32 q-rows/block, 2 blocks/CU) ----------------
// Waves 0-1: QK^T + softmax -> pfr/scs; PV c-half 0. Waves 2-3: PV c-half 1 + K staging + mean.
// Per tile: [A][B][C] -> barrierA -> PV + [H] -> barrierB -> DMA(t+1) (drains at next barrierA).
__global__ __launch_bounds__(256, 3) void k_flash(const float* __restrict__ qT,
                                                  const u16* __restrict__ khi,
                                                  const u16* __restrict__ klo,
                                                  const u16* __restrict__ vT,
                                                  const float* __restrict__ Spart,
                                                  const float* __restrict__ bq,
                                                  const float* __restrict__ bk,
                                                  u16* __restrict__ odsb) {
  __shared__ u16 vbuf[16384];          // 32 KB (single buffer)
  __shared__ u16 kfh[4][64][8];        // 4 KB
  __shared__ u16 kfl[4][64][8];        // 4 KB
  __shared__ u16 pfr[2][2][64][8];     // 4 KB
  __shared__ float scs[2];
  __shared__ float Ls[2][4][4];        // [wq][g][r]
  __shared__ float mean_s;

  const int orig = blockIdx.x;                              // 512 blocks
  const int b    = (orig >> 1) & 3;                         // XCD-locality: each XCD one batch
  const int rowt = ((orig & 1) << 6) | (orig >> 3);         // 0..127, bijective
  const int row0 = rowt * 32;
  const int tid  = threadIdx.x;
  const int w    = tid >> 6;
  const int lane = tid & 63;
  const int wq   = w & 1;
  const int wc   = w >> 1;
  const int g    = lane >> 4;
  const int c16  = lane & 15;
  const bool is_cw = (w < 2);

  // ---- inline mean (on PV wave 2) ----
  if (tid >= 128 && tid < 192) {
    int t64 = tid - 128;
    int bb = t64 >> 4, o = t64 & 15;
    float sq = 4096.0f * bq[o], sk = 4096.0f * bk[o];
    for (int s = 0; s < 64; ++s) {
      const float* p = Spart + ((size_t)(bb * 64 + s)) * 32u;
      sq += p[o];
      sk += p[16 + o];
    }
    float pr = sq * sk;
#pragma unroll
    for (int off = 32; off > 0; off >>= 1) pr += __shfl_down(pr, off);
    if (t64 == 0) mean_s = pr * (1.0f / 67108864.0f);   // / (B*N*N)
  }

  // ---- Q A-frags (split bf16) ----
  float qv[16];
  {
    const float* qrow = qT + ((size_t)b*4096 + row0 + 16*wq + c16) * 16;
#pragma unroll
    for (int i = 0; i < 4; ++i) {
      float4 t4 = reinterpret_cast<const float4*>(qrow)[i];
      qv[4*i] = t4.x; qv[4*i+1] = t4.y; qv[4*i+2] = t4.z; qv[4*i+3] = t4.w;
    }
  }
  u16 qhi[16], qlo[16];
#pragma unroll
  for (int i = 0; i < 16; ++i) {
    __hip_bfloat16 h = __float2bfloat16(qv[i]);
    float fh = __bfloat162float(h);
    __hip_bfloat16 lo = __float2bfloat16(qv[i] - fh);
    qhi[i] = __builtin_bit_cast(u16, h);
    qlo[i] = __builtin_bit_cast(u16, lo);
  }
  us8 a1u, a2u;
  {
    const bool koff8  = (g & 1);
    const bool lo_src = (g >= 2);
#pragma unroll
    for (int i = 0; i < 8; ++i) {
      u16 hs = koff8 ? qhi[i+8] : qhi[i];
      u16 ls = koff8 ? qlo[i+8] : qlo[i];
      a1u[i] = lo_src ? ls : hs;
      a2u[i] = lo_src ? (u16)0 : hs;
    }
  }
  const bf16x8 A1 = __builtin_bit_cast(bf16x8, a1u);
  const bf16x8 A2 = __builtin_bit_cast(bf16x8, a2u);

  f32x4 O[8];
#pragma unroll
  for (int i = 0; i < 8; ++i) O[i] = (f32x4){0.f, 0.f, 0.f, 0.f};
  float Lr[4] = {0.f, 0.f, 0.f, 0.f};
  float M = 0.0f;

  // K staging params (PV threads tid 128..255 handle 2 slots each)
  const int tid2 = tid - 128;
  int ksA[2], kldA[2], kiA[2], kvA[2];
#pragma unroll
  for (int h = 0; h < 2; ++h) {
    int s = tid2 + h * 128;            // 0..255
    int kv_s = s >> 2, t4v = s & 3;
    kvA[h] = kv_s;
    ksA[h] = kv_s >> 4;
    kldA[h] = (kv_s & 15) + 16 * (t4v >> 1);
    kiA[h] = 4 * (t4v & 1);
  }

  // ---- prologue: stage tile 0 ----
  {
    const u16* vsrc = vT + (size_t)b*256*4096;
#pragma unroll
    for (int i = 0; i < 8; ++i) {
      int u = i*256 + tid;
      int row = u >> 3, slot = u & 7;
      int sb = (slot*16) ^ ((row & 7) << 4);
      gl2lds16((const char*)(vsrc + (size_t)row*4096) + sb, (char*)&vbuf[0] + u*16);
    }
    if (tid >= 128) {
#pragma unroll
      for (int h = 0; h < 2; ++h) {
        int s = tid2 + h * 128;
        size_t kb = ((size_t)b*4096 + kvA[h])*16 + 4*(s & 3);
        us4 h4 = *reinterpret_cast<const us4*>(khi + kb);
        us4 l4 = *reinterpret_cast<const us4*>(klo + kb);
        *reinterpret_cast<us4*>(&kfh[ksA[h]][kldA[h]][kiA[h]])      = h4;
        *reinterpret_cast<us4*>(&kfh[ksA[h]][kldA[h]+32][kiA[h]])   = h4;
        *reinterpret_cast<us4*>(&kfl[ksA[h]][kldA[h]][kiA[h]])      = l4;
        *reinterpret_cast<us4*>(&kfl[ksA[h]][kldA[h]+32][kiA[h]])   = l4;
      }
    }
  }
  __syncthreads();
  const float mean = mean_s;

  // ---- main loop over 64 KV tiles of 64 ----
  for (int t = 0; t < 64; ++t) {
    const int kv0n = ((t + 1) & 63) * 64;

    us4 hvec[2], lvec[2];
    if (tid >= 128) {
#pragma unroll
      for (int h = 0; h < 2; ++h) {
        int s = tid2 + h * 128;
        size_t kb = ((size_t)b*4096 + kv0n + kvA[h])*16 + 4*(s & 3);
        hvec[h] = *reinterpret_cast<const us4*>(khi + kb);
        lvec[h] = *reinterpret_cast<const us4*>(klo + kb);
      }
    }

    if (is_cw) {
      // [A] scores (kf holds tile t)
      f32x4 S[4];
#pragma unroll
      for (int s = 0; s < 4; ++s) {
        bf16x8 bh = __builtin_bit_cast(bf16x8, *reinterpret_cast<const us8*>(&kfh[s][lane][0]));
        bf16x8 bl = __builtin_bit_cast(bf16x8, *reinterpret_cast<const us8*>(&kfl[s][lane][0]));
        f32x4 acc = (f32x4){0.f, 0.f, 0.f, 0.f};
        acc = __builtin_amdgcn_mfma_f32_16x16x32_bf16(A1, bh, acc, 0, 0, 0);
        acc = __builtin_amdgcn_mfma_f32_16x16x32_bf16(A2, bl, acc, 0, 0, 0);
        S[s] = acc;
      }

      // [B] mask + deferred-max online softmax
      float pmax = -1e30f;
#pragma unroll
      for (int s = 0; s < 4; ++s)
#pragma unroll
        for (int r = 0; r < 4; ++r) {
          float v = S[s][r];
          v = (v < mean) ? 0.f : v;
          S[s][r] = v;
          pmax = fmaxf(pmax, v);
        }
      float sc_out = 1.0f;
      if (!__all(pmax <= M + 8.0f)) {
        float mw = pmax;
#pragma unroll
        for (int off = 1; off < 64; off <<= 1) mw = fmaxf(mw, __shfl_xor(mw, off));
        float Mn = fmaxf(M, mw);
        float sc = __expf(M - Mn);
#pragma unroll
        for (int i = 0; i < 8; ++i) {
          O[i][0] *= sc; O[i][1] *= sc; O[i][2] *= sc; O[i][3] *= sc;
        }
#pragma unroll
        for (int r = 0; r < 4; ++r) Lr[r] *= sc;
        M = Mn;
        sc_out = sc;
      }
      if (lane == 0) scs[wq] = sc_out;

      u16 pb[4][4];
#pragma unroll
      for (int s = 0; s < 4; ++s)
#pragma unroll
        for (int r = 0; r < 4; ++r) {
          float p = __expf(S[s][r] - M);
          Lr[r] += p;
          pb[s][r] = __builtin_bit_cast(u16, __float2bfloat16(p));
        }

      // [C] write P frags
      {
        const int ib = lane & 7;
        const int t1 = (lane >> 3) & 1;
#pragma unroll
        for (int s = 0; s < 4; ++s) {
          const int c2 = s >> 1;
          const int ldb = 16 * ((2*s + t1) & 3) + 4*g;
#pragma unroll
          for (int r = 0; r < 4; ++r) pfr[wq][c2][ldb + r][ib] = pb[s][r];
        }
      }
    }
    __syncthreads();   // barrierA: pfr/scs visible; previous DMA drained (vbuf = tile t)

    if (!is_cw) {
      float sc = scs[wq];
      if (sc != 1.0f) {
#pragma unroll
        for (int i = 0; i < 8; ++i) {
          O[i][0] *= sc; O[i][1] *= sc; O[i][2] *= sc; O[i][3] *= sc;
        }
      }
    }

    // [G] PV on tile t
#pragma unroll
    for (int c2 = 0; c2 < 2; ++c2) {
      bf16x8 pa = __builtin_bit_cast(bf16x8, *reinterpret_cast<const us8*>(&pfr[wq][c2][lane][0]));
#pragma unroll
      for (int ct = 0; ct < 8; ++ct) {
        int row = (wc*8 + ct)*16 + c16;
        int off = (c2*64 + g*16) ^ ((lane & 7) << 4);
        bf16x8 vb = __builtin_bit_cast(bf16x8,
            *reinterpret_cast<const us8*>((const char*)&vbuf[0] + row*128 + off));
        O[ct] = __builtin_amdgcn_mfma_f32_16x16x32_bf16(pa, vb, O[ct], 0, 0, 0);
      }
    }

    // [H] K frags for tile t+1 (PV waves)
    if (tid >= 128) {
#pragma unroll
      for (int h = 0; h < 2; ++h) {
        *reinterpret_cast<us4*>(&kfh[ksA[h]][kldA[h]][kiA[h]])      = hvec[h];
        *reinterpret_cast<us4*>(&kfh[ksA[h]][kldA[h]+32][kiA[h]])   = hvec[h];
        *reinterpret_cast<us4*>(&kfl[ksA[h]][kldA[h]][kiA[h]])      = lvec[h];
        *reinterpret_cast<us4*>(&kfl[ksA[h]][kldA[h]+32][kiA[h]])   = lvec[h];
      }
    }

    __syncthreads();   // barrierB: PV reads of vbuf done -> safe to overwrite

    if (t < 63) {
      const u16* vsrc = vT + (size_t)b*256*4096 + kv0n;
#pragma unroll
      for (int i = 0; i < 8; ++i) {
        int u = i*256 + tid;
        int row = u >> 3, slot = u & 7;
        int sb = (slot*16) ^ ((row & 7) << 4);
        gl2lds16((const char*)(vsrc + (size_t)row*4096) + sb, (char*)&vbuf[0] + u*16);
      }
    }
  }

  // ---- epilogue: bf16 ods write ----
  if (is_cw) {
#pragma unroll
    for (int r = 0; r < 4; ++r) {
      float v = Lr[r];
#pragma unroll
      for (int off = 1; off < 16; off <<= 1) v += __shfl_xor(v, off);
      Lr[r] = v;
    }
    if (c16 == 0) {
#pragma unroll
      for (int r = 0; r < 4; ++r) Ls[wq][g][r] = Lr[r];
    }
  }
  __syncthreads();
  float inv[4];
  if (is_cw) {
#pragma unroll
    for (int r = 0; r < 4; ++r) inv[r] = 1.0f / Lr[r];
  } else {
#pragma unroll
    for (int r = 0; r < 4; ++r) inv[r] = 1.0f / Ls[wq][g][r];
  }
#pragma unroll
  for (int ct = 0; ct < 8; ++ct) {
    int c = (wc*8 + ct)*16 + c16;
    u16* dst = odsb + ((size_t)b*256 + c) * 4096u + row0 + 16*wq + 4*g;
    us4 o4;
#pragma unroll
    for (int r = 0; r < 4; ++r)
      o4[r] = __builtin_bit_cast(u16, __float2bfloat16(O[ct][r] * inv[r]));
    *reinterpret_cast<us4*>(dst) = o4;
  }
}

// ---------------- bilinear 4x upsample + residual, 4 px/thread (bf16 ods) ----------------
__global__ __launch_bounds__(256) void k_up(const u16* __restrict__ ods, const float* __restrict__ x,
                                            float* __restrict__ out) {
  unsigned idx4 = blockIdx.x * 256u + threadIdx.x;   // < 16777216
  int a  = (int)(idx4 & 63u);
  int i  = (int)((idx4 >> 6) & 255u);
  size_t bc = idx4 >> 14;

  float py = (i + 0.5f) * 0.25f - 0.5f;
  float y0f = floorf(py);
  float wy = py - y0f;
  int y0 = (int)y0f, y1 = y0 + 1;
  y0 = max(y0, 0); y1 = min(y1, 63);

  int xm1 = max(a - 1, 0), xp1 = min(a + 1, 63);

  const u16* r0 = ods + bc * 4096u + y0 * 64;
  const u16* r1 = ods + bc * 4096u + y1 * 64;
  float wy1 = 1.f - wy;
  float vm1 = wy1 * bf2f(r0[xm1]) + wy * bf2f(r1[xm1]);
  float v0  = wy1 * bf2f(r0[a])   + wy * bf2f(r1[a]);
  float vp1 = wy1 * bf2f(r0[xp1]) + wy * bf2f(r1[xp1]);

  float4 xv = *reinterpret_cast<const float4*>(x + (size_t)idx4 * 4u);
  float4 o4;
  o4.x = fmaf(0.375f, vm1, 0.625f * v0) + xv.x;
  o4.y = fmaf(0.125f, vm1, 0.875f * v0) + xv.y;
  o4.z = fmaf(0.875f, v0, 0.125f * vp1) + xv.z;
  o4.w = fmaf(0.625f, v0, 0.375f * vp1) + xv.w;
  *reinterpret_cast<float4*>(out + (size_t)idx4 * 4u) = o4;
}

extern "C" void kernel_launch(void* const* d_in, const int* in_sizes, int n_in,
                              void* d_out, int out_size, void* d_ws, size_t ws_size,
                              hipStream_t stream) {
  const float* x  = (const float*)d_in[0];
  const float* Wq = (const float*)d_in[1];
  const float* bq = (const float*)d_in[2];
  const float* Wk = (const float*)d_in[3];
  const float* bk = (const float*)d_in[4];
  const float* Wv = (const float*)d_in[5];
  const float* bv = (const float*)d_in[6];
  float* out = (float*)d_out;

  char* ws = (char*)d_ws;
  float* xd32  = (float*)(ws + OFF_XD32);   // aliased by bf16 ods after k_qkv
  float* qT    = (float*)(ws + OFF_QT);
  u16*   khi   = (u16*)(ws + OFF_KHI);
  u16*   klo   = (u16*)(ws + OFF_KLO);
  u16*   vT    = (u16*)(ws + OFF_VT);
  u16*   Wf    = (u16*)(ws + OFF_WF);
  float* Spart = (float*)(ws + OFF_SPART);
  u16*   odsb  = (u16*)(ws + OFF_XD32);

  k_pre<<<dim3(16400), dim3(256), 0, stream>>>(x, Wv, xd32, Wf);
  k_qkv<<<dim3(512), dim3(512), 0, stream>>>(xd32, Wf, bv, Wq, bq, Wk, bk, qT, khi, klo, vT, Spart);
  k_flash<<<dim3(512), dim3(256), 0, stream>>>(qT, khi, klo, vT, Spart, bq, bk, odsb);
  k_up<<<dim3(65536), dim3(256), 0, stream>>>(odsb, x, out);
}

// Round 21
// 243.256 us; speedup vs baseline: 1.1305x; 1.1305x over previous
//
#include <hip/hip_runtime.h>
#include <hip/hip_bf16.h>
#include <cmath>
#include <cstdint>
#include <cstddef>

// Problem constants: B=4, C=256, H=W=256, DS=4 -> h=w=64, N=4096, Cq=16
typedef unsigned short u16;
typedef __attribute__((ext_vector_type(8))) __bf16 bf16x8;
typedef __attribute__((ext_vector_type(4))) float f32x4;
typedef __attribute__((ext_vector_type(8))) unsigned short us8;
typedef __attribute__((ext_vector_type(4))) unsigned short us4;

// Workspace layout (bytes)
static const size_t OFF_XD32  = 0;            // [B][C][4096] fp32 xd; aliased by ods (bf16) after k_qkv
static const size_t OFF_QT    = 16777216;     // [B][4096][16] fp32, 1 MB
static const size_t OFF_KHI   = 17825792;     // [B][4096][16] u16 bf16-hi of k, 512 KB
static const size_t OFF_KLO   = 18350080;     // [B][4096][16] u16 bf16-lo of k, 512 KB
static const size_t OFF_VT    = 18874368;     // [B][256][4096] bf16 (V transposed), 8 MB
static const size_t OFF_WF    = 27262976;     // Wv A-frags [16 rt][8 ks][64 lane][8 j] bf16, 128 KB
static const size_t OFF_SPART = 27394048;     // [256 qk-blocks][32] fp32 partial col-sums, 32 KB

__device__ __forceinline__ void gl2lds16(const void* gsrc, void* ldst) {
  __builtin_amdgcn_global_load_lds(
      (const __attribute__((address_space(1))) unsigned int*)gsrc,
      (__attribute__((address_space(3))) unsigned int*)ldst, 16, 0, 0);
}

__device__ __forceinline__ float hmax4(float4 v) {
  return fmaxf(fmaxf(v.x, v.y), fmaxf(v.z, v.w));
}

__device__ __forceinline__ float bf2f(u16 u) {
  return __bfloat162float(__builtin_bit_cast(__hip_bfloat16, u));
}

// ---------------- fused: Wv->A-frags (blocks 0..15) + maxpool (blocks 16..16399) ----------------
__global__ __launch_bounds__(256) void k_pre(const float* __restrict__ x,
                                             const float* __restrict__ Wv,
                                             float* __restrict__ xd32,
                                             u16* __restrict__ Wf) {
  const int tid = threadIdx.x;
  if (blockIdx.x < 16) {
    const int rt = blockIdx.x;
#pragma unroll
    for (int i = 0; i < 2; ++i) {
      int s = tid + i * 256;           // 0..511 = ks*64 + lane
      int ks = s >> 6, lane = s & 63;
      const float* src = Wv + (size_t)(rt * 16 + (lane & 15)) * 256u + ks * 32 + (lane >> 4) * 8;
      float4 a = *reinterpret_cast<const float4*>(src);
      float4 b = *reinterpret_cast<const float4*>(src + 4);
      us8 o;
      o[0] = __builtin_bit_cast(u16, __float2bfloat16(a.x));
      o[1] = __builtin_bit_cast(u16, __float2bfloat16(a.y));
      o[2] = __builtin_bit_cast(u16, __float2bfloat16(a.z));
      o[3] = __builtin_bit_cast(u16, __float2bfloat16(a.w));
      o[4] = __builtin_bit_cast(u16, __float2bfloat16(b.x));
      o[5] = __builtin_bit_cast(u16, __float2bfloat16(b.y));
      o[6] = __builtin_bit_cast(u16, __float2bfloat16(b.z));
      o[7] = __builtin_bit_cast(u16, __float2bfloat16(b.w));
      *reinterpret_cast<us8*>(Wf + ((size_t)((rt * 8 + ks) * 64 + lane)) * 8u) = o;
    }
  } else {
    unsigned idx = (blockIdx.x - 16) * 256u + tid;     // < 4*256*64*64
    unsigned xo = idx & 63u;
    unsigned yo = (idx >> 6) & 63u;
    unsigned bc = idx >> 12;                           // b*256 + c
    const float* base = x + (size_t)bc * 65536u + yo * 1024u + xo * 4u;
    float m = -1e30f;
#pragma unroll
    for (int dy = 0; dy < 4; ++dy) {
      float4 v = *reinterpret_cast<const float4*>(base + dy * 256);
      m = fmaxf(m, hmax4(v));
    }
    xd32[(size_t)bc * 4096u + yo * 64u + xo] = m;
  }
}

// ---------------- fused q/k convs + V MFMA gemm (block-role split) ----------------
__global__ __launch_bounds__(512) void k_qkv(const float* __restrict__ xd32,
                                             const u16* __restrict__ Wf, const float* __restrict__ bv,
                                             const float* __restrict__ Wq, const float* __restrict__ bq,
                                             const float* __restrict__ Wk, const float* __restrict__ bk,
                                             float* __restrict__ qT,
                                             u16* __restrict__ khi, u16* __restrict__ klo,
                                             u16* __restrict__ vT, float* __restrict__ Spart) {
  __shared__ char smem[65536];
  const int tid = threadIdx.x;

  if (blockIdx.x < 256) {
    // ---------- vgemm role ----------
    u16 (*Bf)[8][64][8] = reinterpret_cast<u16(*)[8][64][8]>(smem);   // 32 KB
    const int blk = blockIdx.x;
    const int b = blk >> 6, n0 = (blk & 63) * 64;
    const int w = tid >> 6, lane = tid & 63;

#pragma unroll
    for (int p = 0; p < 8; ++p) {
      int idx = p * 512 + tid;         // 0..4095 float4 slots
      int k = idx >> 4, q4 = idx & 15;
      float4 v = *reinterpret_cast<const float4*>(
          xd32 + ((size_t)b * 256 + k) * 4096u + n0 + q4 * 4);
      int ks = k >> 5, kl = (k >> 3) & 3, j = k & 7;
      int ct = q4 >> 2, nb = (q4 & 3) * 4;
      Bf[ct][ks][kl * 16 + nb + 0][j] = __builtin_bit_cast(u16, __float2bfloat16(v.x));
      Bf[ct][ks][kl * 16 + nb + 1][j] = __builtin_bit_cast(u16, __float2bfloat16(v.y));
      Bf[ct][ks][kl * 16 + nb + 2][j] = __builtin_bit_cast(u16, __float2bfloat16(v.z));
      Bf[ct][ks][kl * 16 + nb + 3][j] = __builtin_bit_cast(u16, __float2bfloat16(v.w));
    }
    __syncthreads();

    f32x4 acc[2][4];
#pragma unroll
    for (int r = 0; r < 2; ++r)
#pragma unroll
      for (int ct = 0; ct < 4; ++ct) acc[r][ct] = (f32x4){0.f, 0.f, 0.f, 0.f};
    for (int ks = 0; ks < 8; ++ks) {
      bf16x8 Bv[4];
#pragma unroll
      for (int ct = 0; ct < 4; ++ct)
        Bv[ct] = __builtin_bit_cast(bf16x8, *reinterpret_cast<const us8*>(&Bf[ct][ks][lane][0]));
#pragma unroll
      for (int r = 0; r < 2; ++r) {
        int rt = w * 2 + r;
        bf16x8 Av = __builtin_bit_cast(bf16x8,
            *reinterpret_cast<const us8*>(Wf + ((size_t)((rt * 8 + ks) * 64 + lane)) * 8u));
#pragma unroll
        for (int ct = 0; ct < 4; ++ct)
          acc[r][ct] = __builtin_amdgcn_mfma_f32_16x16x32_bf16(Av, Bv[ct], acc[r][ct], 0, 0, 0);
      }
    }

#pragma unroll
    for (int r = 0; r < 2; ++r) {
      int row0 = (w * 2 + r) * 16 + (lane >> 4) * 4;
#pragma unroll
      for (int rr = 0; rr < 4; ++rr) {
        int c = row0 + rr;
        float bb = bv[c];
        u16* dst = vT + ((size_t)b * 256 + c) * 4096u + n0 + (lane & 15);
#pragma unroll
        for (int ct = 0; ct < 4; ++ct)
          dst[ct * 16] = __builtin_bit_cast(u16, __float2bfloat16(acc[r][ct][rr] + bb));
      }
    }
  } else {
    // ---------- qk role: fp32 exact convs + col sums; k stored pre-split hi/lo ----------
    float (*xs)[64] = reinterpret_cast<float(*)[64]>(smem);   // 64 KB
    const int qb = blockIdx.x - 256;
    const int b = qb >> 6, n0 = (qb & 63) * 64;
    {
      const float* src = xd32 + (size_t)b * 1048576u + n0;
#pragma unroll
      for (int i = 0; i < 8; ++i) {
        int slot = tid + i * 512;      // 0..4095 float4 slots
        int c = slot >> 4, q4 = slot & 15;
        *reinterpret_cast<float4*>(&xs[c][q4 * 4]) =
            *reinterpret_cast<const float4*>(src + (size_t)c * 4096u + q4 * 4);
      }
    }
    __syncthreads();
    const int o = tid >> 4, t4 = tid & 15;   // o 0..31; tokens t4*4..+4
    const float* wrow = (o < 16) ? (Wq + (size_t)o * 256u) : (Wk + (size_t)(o - 16) * 256u);
    float a0 = 0.f, a1 = 0.f, a2 = 0.f, a3 = 0.f;
    for (int c = 0; c < 256; ++c) {
      float w = wrow[c];
      float4 xv = *reinterpret_cast<const float4*>(&xs[c][t4 * 4]);
      a0 = fmaf(w, xv.x, a0);
      a1 = fmaf(w, xv.y, a1);
      a2 = fmaf(w, xv.z, a2);
      a3 = fmaf(w, xv.w, a3);
    }
    int oo = (o < 16) ? o : (o - 16);
    float bb = (o < 16) ? bq[oo] : bk[oo];
    float v0 = a0 + bb, v1 = a1 + bb, v2 = a2 + bb, v3 = a3 + bb;
    size_t base = ((size_t)b * 4096u + n0 + t4 * 4) * 16u + oo;
    if (o < 16) {
      qT[base]      = v0;
      qT[base + 16] = v1;
      qT[base + 32] = v2;
      qT[base + 48] = v3;
    } else {
      float vv[4] = {v0, v1, v2, v3};
#pragma unroll
      for (int j = 0; j < 4; ++j) {
        __hip_bfloat16 h = __float2bfloat16(vv[j]);
        float fh = __bfloat162float(h);
        __hip_bfloat16 lo = __float2bfloat16(vv[j] - fh);
        khi[base + 16 * j] = __builtin_bit_cast(u16, h);
        klo[base + 16 * j] = __builtin_bit_cast(u16, lo);
      }
    }
    float s = a0 + a1 + a2 + a3;
    s += __shfl_xor(s, 1); s += __shfl_xor(s, 2);
    s += __shfl_xor(s, 4); s += __shfl_xor(s, 8);
    if (t4 == 0) Spart[(size_t)qb * 32u + o] = s;
  }
}

// ---------------- one-pass MFMA flash: single-buffered LDS (48 KB -> 2-3 blocks/CU) ----------------
// Waves 0-3: QK^T + softmax -> pfr/scs; PV c-half 0.
// Waves 4-7: PV c-half 1 + K staging + mean.
// Per tile: [A][B][C] -> barrierA -> PV + [H] -> barrierB -> DMA(t+1) (drains at next barrierA).
__global__ __launch_bounds__(512, 4) void k_flash(const float* __restrict__ qT,
                                                  const u16* __restrict__ khi,
                                                  const u16* __restrict__ klo,
                                                  const u16* __restrict__ vT,
                                                  const float* __restrict__ Spart,
                                                  const float* __restrict__ bq,
                                                  const float* __restrict__ bk,
                                                  u16* __restrict__ odsb) {
  __shared__ u16 vbuf[16384];          // 32 KB (single buffer)
  __shared__ u16 kfh[4][64][8];        // 4 KB (single buffer)
  __shared__ u16 kfl[4][64][8];        // 4 KB
  __shared__ u16 pfr[4][2][64][8];     // 8 KB
  __shared__ float scs[4];
  __shared__ float Ls[4][4][4];        // [wq][g][r]
  __shared__ float mean_s;

  const int orig = blockIdx.x;
  const int b    = (orig >> 1) & 3;
  const int row0 = (((orig & 1) << 5) | (orig >> 3)) * 64;
  const int tid  = threadIdx.x;
  const int w    = tid >> 6;
  const int lane = tid & 63;
  const int wq   = w & 3;
  const int wc   = w >> 2;
  const int g    = lane >> 4;
  const int c16  = lane & 15;
  const bool is_cw = (w < 4);

  // ---- inline mean (on a PV wave) ----
  if (tid >= 256 && tid < 320) {
    int t64 = tid - 256;
    int bb = t64 >> 4, o = t64 & 15;
    float sq = 4096.0f * bq[o], sk = 4096.0f * bk[o];
    for (int s = 0; s < 64; ++s) {
      const float* p = Spart + ((size_t)(bb * 64 + s)) * 32u;
      sq += p[o];
      sk += p[16 + o];
    }
    float pr = sq * sk;
#pragma unroll
    for (int off = 32; off > 0; off >>= 1) pr += __shfl_down(pr, off);
    if (t64 == 0) mean_s = pr * (1.0f / 67108864.0f);   // / (B*N*N)
  }

  // ---- Q A-frags (split bf16) ----
  float qv[16];
  {
    const float* qrow = qT + ((size_t)b*4096 + row0 + 16*wq + c16) * 16;
#pragma unroll
    for (int i = 0; i < 4; ++i) {
      float4 t4 = reinterpret_cast<const float4*>(qrow)[i];
      qv[4*i] = t4.x; qv[4*i+1] = t4.y; qv[4*i+2] = t4.z; qv[4*i+3] = t4.w;
    }
  }
  u16 qhi[16], qlo[16];
#pragma unroll
  for (int i = 0; i < 16; ++i) {
    __hip_bfloat16 h = __float2bfloat16(qv[i]);
    float fh = __bfloat162float(h);
    __hip_bfloat16 lo = __float2bfloat16(qv[i] - fh);
    qhi[i] = __builtin_bit_cast(u16, h);
    qlo[i] = __builtin_bit_cast(u16, lo);
  }
  us8 a1u, a2u;
  {
    const bool koff8  = (g & 1);
    const bool lo_src = (g >= 2);
#pragma unroll
    for (int i = 0; i < 8; ++i) {
      u16 hs = koff8 ? qhi[i+8] : qhi[i];
      u16 ls = koff8 ? qlo[i+8] : qlo[i];
      a1u[i] = lo_src ? ls : hs;
      a2u[i] = lo_src ? (u16)0 : hs;
    }
  }
  const bf16x8 A1 = __builtin_bit_cast(bf16x8, a1u);
  const bf16x8 A2 = __builtin_bit_cast(bf16x8, a2u);

  f32x4 O[8];
#pragma unroll
  for (int i = 0; i < 8; ++i) O[i] = (f32x4){0.f, 0.f, 0.f, 0.f};
  float Lr[4] = {0.f, 0.f, 0.f, 0.f};
  float M = 0.0f;

  // K staging params (PV-wave threads: tid 256..511)
  const int tid2 = tid - 256;
  const int kv_s = tid2 >> 2, t4v = tid2 & 3;
  const int ks = kv_s >> 4, kld0 = (kv_s & 15) + 16*(t4v >> 1), ki0 = 4*(t4v & 1);

  // ---- prologue: stage tile 0 (V DMA + K frags), drain at first barrier ----
  {
    const u16* vsrc = vT + (size_t)b*256*4096;
#pragma unroll
    for (int i = 0; i < 4; ++i) {
      int u = i*512 + tid;
      int row = u >> 3, slot = u & 7;
      int sb = (slot*16) ^ ((row & 7) << 4);
      gl2lds16((const char*)(vsrc + (size_t)row*4096) + sb, (char*)&vbuf[0] + u*16);
    }
    if (tid >= 256) {
      size_t kb = ((size_t)b*4096 + kv_s)*16 + 4*t4v;
      us4 h4 = *reinterpret_cast<const us4*>(khi + kb);
      us4 l4 = *reinterpret_cast<const us4*>(klo + kb);
      *reinterpret_cast<us4*>(&kfh[ks][kld0][ki0])    = h4;
      *reinterpret_cast<us4*>(&kfh[ks][kld0+32][ki0]) = h4;
      *reinterpret_cast<us4*>(&kfl[ks][kld0][ki0])    = l4;
      *reinterpret_cast<us4*>(&kfl[ks][kld0+32][ki0]) = l4;
    }
  }
  __syncthreads();
  const float mean = mean_s;

  // ---- main loop over 64 KV tiles of 64 ----
  for (int t = 0; t < 64; ++t) {
    const int kv0n = ((t + 1) & 63) * 64;

    // K regs for tile t+1 (PV waves)
    us4 hvec, lvec;
    if (tid >= 256) {
      size_t kb = ((size_t)b*4096 + kv0n + kv_s)*16 + 4*t4v;
      hvec = *reinterpret_cast<const us4*>(khi + kb);
      lvec = *reinterpret_cast<const us4*>(klo + kb);
    }

    if (is_cw) {
      // [A] scores (kf holds tile t)
      f32x4 S[4];
#pragma unroll
      for (int s = 0; s < 4; ++s) {
        bf16x8 bh = __builtin_bit_cast(bf16x8, *reinterpret_cast<const us8*>(&kfh[s][lane][0]));
        bf16x8 bl = __builtin_bit_cast(bf16x8, *reinterpret_cast<const us8*>(&kfl[s][lane][0]));
        f32x4 acc = (f32x4){0.f, 0.f, 0.f, 0.f};
        acc = __builtin_amdgcn_mfma_f32_16x16x32_bf16(A1, bh, acc, 0, 0, 0);
        acc = __builtin_amdgcn_mfma_f32_16x16x32_bf16(A2, bl, acc, 0, 0, 0);
        S[s] = acc;
      }

      // [B] mask + deferred-max online softmax
      float pmax = -1e30f;
#pragma unroll
      for (int s = 0; s < 4; ++s)
#pragma unroll
        for (int r = 0; r < 4; ++r) {
          float v = S[s][r];
          v = (v < mean) ? 0.f : v;
          S[s][r] = v;
          pmax = fmaxf(pmax, v);
        }
      float sc_out = 1.0f;
      if (!__all(pmax <= M + 8.0f)) {
        float mw = pmax;
#pragma unroll
        for (int off = 1; off < 64; off <<= 1) mw = fmaxf(mw, __shfl_xor(mw, off));
        float Mn = fmaxf(M, mw);
        float sc = __expf(M - Mn);
#pragma unroll
        for (int i = 0; i < 8; ++i) {
          O[i][0] *= sc; O[i][1] *= sc; O[i][2] *= sc; O[i][3] *= sc;
        }
#pragma unroll
        for (int r = 0; r < 4; ++r) Lr[r] *= sc;
        M = Mn;
        sc_out = sc;
      }
      if (lane == 0) scs[wq] = sc_out;

      u16 pb[4][4];
#pragma unroll
      for (int s = 0; s < 4; ++s)
#pragma unroll
        for (int r = 0; r < 4; ++r) {
          float p = __expf(S[s][r] - M);
          Lr[r] += p;
          pb[s][r] = __builtin_bit_cast(u16, __float2bfloat16(p));
        }

      // [C] write P frags
      {
        const int ib = lane & 7;
        const int t1 = (lane >> 3) & 1;
#pragma unroll
        for (int s = 0; s < 4; ++s) {
          const int c2 = s >> 1;
          const int ldb = 16 * ((2*s + t1) & 3) + 4*g;
#pragma unroll
          for (int r = 0; r < 4; ++r) pfr[wq][c2][ldb + r][ib] = pb[s][r];
        }
      }
    }
    __syncthreads();   // barrierA: pfr/scs visible; previous DMA drained (vbuf = tile t)

    if (!is_cw) {
      float sc = scs[wq];
      if (sc != 1.0f) {
#pragma unroll
        for (int i = 0; i < 8; ++i) {
          O[i][0] *= sc; O[i][1] *= sc; O[i][2] *= sc; O[i][3] *= sc;
        }
      }
    }

    // [G] PV on tile t (reads vbuf)
#pragma unroll
    for (int c2 = 0; c2 < 2; ++c2) {
      bf16x8 pa = __builtin_bit_cast(bf16x8, *reinterpret_cast<const us8*>(&pfr[wq][c2][lane][0]));
#pragma unroll
      for (int ct = 0; ct < 8; ++ct) {
        int row = (wc*8 + ct)*16 + c16;
        int off = (c2*64 + g*16) ^ ((lane & 7) << 4);
        bf16x8 vb = __builtin_bit_cast(bf16x8,
            *reinterpret_cast<const us8*>((const char*)&vbuf[0] + row*128 + off));
        O[ct] = __builtin_amdgcn_mfma_f32_16x16x32_bf16(pa, vb, O[ct], 0, 0, 0);
      }
    }

    // [H] K frags for tile t+1 (PV waves; kf reads for tile t finished before barrierA)
    if (tid >= 256) {
      *reinterpret_cast<us4*>(&kfh[ks][kld0][ki0])    = hvec;
      *reinterpret_cast<us4*>(&kfh[ks][kld0+32][ki0]) = hvec;
      *reinterpret_cast<us4*>(&kfl[ks][kld0][ki0])    = lvec;
      *reinterpret_cast<us4*>(&kfl[ks][kld0+32][ki0]) = lvec;
    }

    __syncthreads();   // barrierB: PV reads of vbuf done -> safe to overwrite

    // DMA tile t+1 into vbuf; overlaps next tile's [A][B][C]; drained at next barrierA
    if (t < 63) {
      const u16* vsrc = vT + (size_t)b*256*4096 + kv0n;
#pragma unroll
      for (int i = 0; i < 4; ++i) {
        int u = i*512 + tid;
        int row = u >> 3, slot = u & 7;
        int sb = (slot*16) ^ ((row & 7) << 4);
        gl2lds16((const char*)(vsrc + (size_t)row*4096) + sb, (char*)&vbuf[0] + u*16);
      }
    }
  }

  // ---- epilogue: bf16 ods write ----
  if (is_cw) {
#pragma unroll
    for (int r = 0; r < 4; ++r) {
      float v = Lr[r];
#pragma unroll
      for (int off = 1; off < 16; off <<= 1) v += __shfl_xor(v, off);
      Lr[r] = v;
    }
    if (c16 == 0) {
#pragma unroll
      for (int r = 0; r < 4; ++r) Ls[wq][g][r] = Lr[r];
    }
  }
  __syncthreads();
  float inv[4];
  if (is_cw) {
#pragma unroll
    for (int r = 0; r < 4; ++r) inv[r] = 1.0f / Lr[r];
  } else {
#pragma unroll
    for (int r = 0; r < 4; ++r) inv[r] = 1.0f / Ls[wq][g][r];
  }
#pragma unroll
  for (int ct = 0; ct < 8; ++ct) {
    int c = (wc*8 + ct)*16 + c16;
    u16* dst = odsb + ((size_t)b*256 + c) * 4096u + row0 + 16*wq + 4*g;
    us4 o4;
#pragma unroll
    for (int r = 0; r < 4; ++r)
      o4[r] = __builtin_bit_cast(u16, __float2bfloat16(O[ct][r] * inv[r]));
    *reinterpret_cast<us4*>(dst) = o4;
  }
}

// ---------------- bilinear 4x upsample + residual, 4 px/thread (bf16 ods) ----------------
__global__ __launch_bounds__(256) void k_up(const u16* __restrict__ ods, const float* __restrict__ x,
                                            float* __restrict__ out) {
  unsigned idx4 = blockIdx.x * 256u + threadIdx.x;   // < 16777216
  int a  = (int)(idx4 & 63u);
  int i  = (int)((idx4 >> 6) & 255u);
  size_t bc = idx4 >> 14;

  float py = (i + 0.5f) * 0.25f - 0.5f;
  float y0f = floorf(py);
  float wy = py - y0f;
  int y0 = (int)y0f, y1 = y0 + 1;
  y0 = max(y0, 0); y1 = min(y1, 63);

  int xm1 = max(a - 1, 0), xp1 = min(a + 1, 63);

  const u16* r0 = ods + bc * 4096u + y0 * 64;
  const u16* r1 = ods + bc * 4096u + y1 * 64;
  float wy1 = 1.f - wy;
  float vm1 = wy1 * bf2f(r0[xm1]) + wy * bf2f(r1[xm1]);
  float v0  = wy1 * bf2f(r0[a])   + wy * bf2f(r1[a]);
  float vp1 = wy1 * bf2f(r0[xp1]) + wy * bf2f(r1[xp1]);

  float4 xv = *reinterpret_cast<const float4*>(x + (size_t)idx4 * 4u);
  float4 o4;
  o4.x = fmaf(0.375f, vm1, 0.625f * v0) + xv.x;
  o4.y = fmaf(0.125f, vm1, 0.875f * v0) + xv.y;
  o4.z = fmaf(0.875f, v0, 0.125f * vp1) + xv.z;
  o4.w = fmaf(0.625f, v0, 0.375f * vp1) + xv.w;
  *reinterpret_cast<float4*>(out + (size_t)idx4 * 4u) = o4;
}

extern "C" void kernel_launch(void* const* d_in, const int* in_sizes, int n_in,
                              void* d_out, int out_size, void* d_ws, size_t ws_size,
                              hipStream_t stream) {
  const float* x  = (const float*)d_in[0];
  const float* Wq = (const float*)d_in[1];
  const float* bq = (const float*)d_in[2];
  const float* Wk = (const float*)d_in[3];
  const float* bk = (const float*)d_in[4];
  const float* Wv = (const float*)d_in[5];
  const float* bv = (const float*)d_in[6];
  float* out = (float*)d_out;

  char* ws = (char*)d_ws;
  float* xd32  = (float*)(ws + OFF_XD32);   // aliased by bf16 ods after k_qkv
  float* qT    = (float*)(ws + OFF_QT);
  u16*   khi   = (u16*)(ws + OFF_KHI);
  u16*   klo   = (u16*)(ws + OFF_KLO);
  u16*   vT    = (u16*)(ws + OFF_VT);
  u16*   Wf    = (u16*)(ws + OFF_WF);
  float* Spart = (float*)(ws + OFF_SPART);
  u16*   odsb  = (u16*)(ws + OFF_XD32);

  k_pre<<<dim3(16400), dim3(256), 0, stream>>>(x, Wv, xd32, Wf);
  k_qkv<<<dim3(512), dim3(512), 0, stream>>>(xd32, Wf, bv, Wq, bq, Wk, bk, qT, khi, klo, vT, Spart);
  k_flash<<<dim3(256), dim3(512), 0, stream>>>(qT, khi, klo, vT, Spart, bq, bk, odsb);
  k_up<<<dim3(65536), dim3(256), 0, stream>>>(odsb, x, out);
}